// Round 5
// baseline (4277.522 us; speedup 1.0000x reference)
//
#include <hip/hip_runtime.h>
#include <hip/hip_bf16.h>
#include <cstdio>
#include <cstdint>

#define BB   4
#define SS   2048
#define DIMM 2048
#define HH   16
#define NOPED 128
#define QKD  192
#define KVR  512
#define DQK  576
#define SCALE_F 0.07216878364870323f  // 192^-0.5

typedef __attribute__((ext_vector_type(4))) float f32x4;
typedef __attribute__((ext_vector_type(8))) __bf16 bf16x8;
typedef __attribute__((ext_vector_type(8))) unsigned short u16x8;

__device__ __forceinline__ f32x4 mfma16(bf16x8 a, bf16x8 b, f32x4 c) {
  return __builtin_amdgcn_mfma_f32_16x16x32_bf16(a, b, c, 0, 0, 0);
}

// async global->LDS, 16B per lane; LDS dest must be wave-uniform base + lane*16
__device__ __forceinline__ void gl16(const __bf16* g, __bf16* l) {
  __builtin_amdgcn_global_load_lds(
      (const __attribute__((address_space(1))) unsigned int*)g,
      (__attribute__((address_space(3))) unsigned int*)l, 16, 0, 0);
}

// ---------------- f32 -> bf16 convert ----------------
__global__ void k_cvt(const float* __restrict__ in, __bf16* __restrict__ out, int n) {
  int i = (blockIdx.x * 256 + threadIdx.x) * 8;
  if (i >= n) return;
  float4 a = *(const float4*)(in + i);
  float4 b = *(const float4*)(in + i + 4);
  bf16x8 v;
  v[0] = (__bf16)a.x; v[1] = (__bf16)a.y; v[2] = (__bf16)a.z; v[3] = (__bf16)a.w;
  v[4] = (__bf16)b.x; v[5] = (__bf16)b.y; v[6] = (__bf16)b.z; v[7] = (__bf16)b.w;
  *(bf16x8*)(out + i) = v;
}

// ---------------- f32 transpose -> bf16 (batched) ----------------
__global__ void k_tr(const float* __restrict__ in, __bf16* __restrict__ out,
                     int R, int C, int64_t inBS, int64_t outBS) {
  in  += (int64_t)blockIdx.z * inBS;
  out += (int64_t)blockIdx.z * outBS;
  __shared__ float t[32][33];
  int c0 = blockIdx.x * 32, r0 = blockIdx.y * 32;
#pragma unroll
  for (int i = 0; i < 4; i++) {
    int r = r0 + threadIdx.y + i * 8, c = c0 + threadIdx.x;
    if (r < R && c < C) t[threadIdx.y + i * 8][threadIdx.x] = in[(int64_t)r * C + c];
  }
  __syncthreads();
#pragma unroll
  for (int i = 0; i < 4; i++) {
    int c = c0 + threadIdx.y + i * 8, r = r0 + threadIdx.x;
    if (c < C && r < R) out[(int64_t)c * R + r] = (__bf16)t[threadIdx.x][threadIdx.y + i * 8];
  }
}

// ---------------- generic batched MFMA GEMM: C = scale * A(M,K) x Bt(N,K)^T ----------------
template <bool OUTF32>
__global__ __launch_bounds__(256) void k_gemm(
    const __bf16* __restrict__ A, const __bf16* __restrict__ Bt, void* __restrict__ Cv,
    int N, int K, int lda, int ldb, int ldc,
    int64_t aSB, int64_t aSH, int64_t bSH, int64_t cSB, int64_t cSH, int Hdiv, float scale) {
  const int z = blockIdx.z;
  const int zb = z / Hdiv, zh = z % Hdiv;
  const int64_t aBase = zb * aSB + zh * aSH;
  const int64_t bBase = zh * bSH;
  const int64_t cBase = zb * cSB + zh * cSH;
  const int n0 = blockIdx.x * 128, m0 = blockIdx.y * 128;
  const int tid = threadIdx.x, lane = tid & 63, wid = tid >> 6;
  const int p = lane & 15, g = lane >> 4;
  const int wr = (wid >> 1) * 64, wc = (wid & 1) * 64;
  __shared__ alignas(16) __bf16 lA[128 * 40];
  __shared__ alignas(16) __bf16 lB[128 * 40];
  const f32x4 fz = {};
  f32x4 acc[4][4];
#pragma unroll
  for (int i = 0; i < 4; i++)
#pragma unroll
    for (int j = 0; j < 4; j++) acc[i][j] = fz;
  const int srow = tid >> 1, shf = tid & 1;
  const __bf16* gA = A + aBase + (int64_t)(m0 + srow) * lda + shf * 16;
  const __bf16* gB = Bt + bBase + (int64_t)(n0 + srow) * ldb + shf * 16;
  const bool bok = (n0 + srow) < N;
  for (int kt = 0; kt < K; kt += 32) {
    u16x8 a0 = *(const u16x8*)(gA + kt);
    u16x8 a1 = *(const u16x8*)(gA + kt + 8);
    u16x8 b0 = {}, b1 = {};
    if (bok) { b0 = *(const u16x8*)(gB + kt); b1 = *(const u16x8*)(gB + kt + 8); }
    __syncthreads();
    *(u16x8*)&lA[srow * 40 + shf * 16]     = a0;
    *(u16x8*)&lA[srow * 40 + shf * 16 + 8] = a1;
    *(u16x8*)&lB[srow * 40 + shf * 16]     = b0;
    *(u16x8*)&lB[srow * 40 + shf * 16 + 8] = b1;
    __syncthreads();
    bf16x8 af[4], bfr[4];
#pragma unroll
    for (int mi = 0; mi < 4; mi++) af[mi]  = *(const bf16x8*)&lA[(wr + mi * 16 + p) * 40 + g * 8];
#pragma unroll
    for (int ni = 0; ni < 4; ni++) bfr[ni] = *(const bf16x8*)&lB[(wc + ni * 16 + p) * 40 + g * 8];
#pragma unroll
    for (int mi = 0; mi < 4; mi++)
#pragma unroll
      for (int ni = 0; ni < 4; ni++) acc[mi][ni] = mfma16(af[mi], bfr[ni], acc[mi][ni]);
  }
#pragma unroll
  for (int mi = 0; mi < 4; mi++) {
#pragma unroll
    for (int ni = 0; ni < 4; ni++) {
      const int n = n0 + wc + ni * 16 + p;
      if (n < N) {
#pragma unroll
        for (int r = 0; r < 4; r++) {
          const int m = m0 + wr + mi * 16 + g * 4 + r;
          float v = acc[mi][ni][r] * scale;
          if (OUTF32) ((float*)Cv)[cBase + (int64_t)m * ldc + n] = v;
          else        ((__bf16*)Cv)[cBase + (int64_t)m * ldc + n] = (__bf16)v;
        }
      }
    }
  }
}

// ---------------- kv prep ----------------
__global__ __launch_bounds__(64) void k_kvprep(
    const __bf16* __restrict__ kvfull, const float* __restrict__ wnorm,
    const float* __restrict__ fc, const float* __restrict__ fs,
    __bf16* __restrict__ Kcat, __bf16* __restrict__ Vt) {
  const int row = blockIdx.x;
  const int lane = threadIdx.x;
  const int b = row >> 11, s = row & 2047;
  const __bf16* src = kvfull + (int64_t)row * DQK;
  bf16x8 v = *(const bf16x8*)(src + lane * 8);
  float f[8], ss = 0.f;
#pragma unroll
  for (int j = 0; j < 8; j++) { f[j] = (float)v[j]; ss += f[j] * f[j]; }
#pragma unroll
  for (int mk = 1; mk < 64; mk <<= 1) ss += __shfl_xor(ss, mk, 64);
  float rn = rsqrtf(ss * (1.f / 512.f) + 1e-6f);
  bf16x8 o;
#pragma unroll
  for (int j = 0; j < 8; j++) o[j] = (__bf16)(f[j] * rn * wnorm[lane * 8 + j]);
  *(bf16x8*)(Kcat + (int64_t)row * DQK + lane * 8) = o;
#pragma unroll
  for (int j = 0; j < 8; j++) Vt[((int64_t)b * KVR + lane * 8 + j) * SS + s] = o[j];
  if (lane < 32) {
    float xr = (float)src[512 + 2 * lane];
    float xi = (float)src[512 + 2 * lane + 1];
    float c = fc[s * 32 + lane], sn = fs[s * 32 + lane];
    Kcat[(int64_t)row * DQK + 512 + 2 * lane]     = (__bf16)(xr * c - xi * sn);
    Kcat[(int64_t)row * DQK + 512 + 2 * lane + 1] = (__bf16)(xr * sn + xi * c);
  }
}

// ---------------- q rope ----------------
__global__ void k_qpe(const __bf16* __restrict__ qfull, const float* __restrict__ fc,
                      const float* __restrict__ fs, __bf16* __restrict__ Qcat) {
  int idx = blockIdx.x * 256 + threadIdx.x;
  if (idx >= BB * HH * SS * 32) return;
  int i = idx & 31, s = (idx >> 5) & 2047, h = (idx >> 16) & 15, b = idx >> 20;
  const __bf16* src = qfull + ((int64_t)(b * SS + s)) * 3072 + h * QKD + NOPED;
  float xr = (float)src[2 * i], xi = (float)src[2 * i + 1];
  float c = fc[s * 32 + i], sn = fs[s * 32 + i];
  __bf16* dst = Qcat + (((int64_t)(b * HH + h)) * SS + s) * DQK + 512;
  dst[2 * i]     = (__bf16)((xr * c - xi * sn) * SCALE_F);
  dst[2 * i + 1] = (__bf16)((xr * sn + xi * c) * SCALE_F);
}

// ---------------- flash attention v5 ----------------
// Single-buffered K and V -> LDS 76 KB -> 2 blocks/CU (the co-resident block
// hides all load/softmax/barrier gaps; both resident blocks share z -> same b
// -> K/V L2-shared). Next tile issued after the end-of-step barrier, waited
// with vmcnt(0) at the next top. V swizzle key (c&3) -> ((c>>1)&3): conflict-
// free under the 8-lane-phase bank model (key applied on BOTH the pre-swizzled
// global source and the read, rule 21). Output in place over Qcat[:, 0:512].
__global__ __launch_bounds__(512, 4) void k_attn(
    const __bf16* __restrict__ Qcat, const __bf16* __restrict__ Kcat,
    const __bf16* __restrict__ Vt, __bf16* __restrict__ Olat) {
  const int z = blockIdx.x;
  const int y = blockIdx.y;
  const int bx = (y < 4) ? y : (y < 8) ? 19 - y : (y < 12) ? y - 4 : 23 - y;
  const int b = z >> 4;
  const int q0 = bx * 128;
  const int tid = threadIdx.x, lane = tid & 63, wid = tid >> 6;
  const int p = lane & 15, g = lane >> 4;
  const int qw = q0 + wid * 16;
  __shared__ alignas(16) __bf16 lK[32 * 576];   // 36864 B
  __shared__ alignas(16) __bf16 lV[512 * 32];   // 32768 B
  __shared__ alignas(16) __bf16 lP[8 * 512];    //  8192 B  (total 77824)

  // ---- step-invariant staging offsets (linear dest, source-side swizzle) ----
  int kSrc[5], vSrc[4];
#pragma unroll
  for (int it = 0; it < 5; it++) {
    int slot = (it < 4) ? it * 512 + tid : 2048 + tid;
    int row = slot / 72, u = slot - row * 72;
    kSrc[it] = row * DQK + ((u ^ (row & 7)) * 8);
  }
#pragma unroll
  for (int it = 0; it < 4; it++) {
    int slot = it * 512 + tid;
    int c = slot >> 2, u = slot & 3;
    vSrc[it] = c * SS + ((u ^ ((c >> 1) & 3)) * 8);
  }

  // ---- Q hoist ----
  bf16x8 qreg[18];
  {
    const __bf16* qb = Qcat + ((int64_t)z * SS + qw + p) * DQK + g * 8;
#pragma unroll
    for (int kc = 0; kc < 18; kc++) qreg[kc] = *(const bf16x8*)(qb + kc * 32);
  }
  const f32x4 fz = {};
  f32x4 acc[32];
#pragma unroll
  for (int ct = 0; ct < 32; ct++) acc[ct] = fz;
  float mrun[4] = {-1e30f, -1e30f, -1e30f, -1e30f};
  float lrun[4] = {0.f, 0.f, 0.f, 0.f};

  const __bf16* kBase = Kcat + (int64_t)b * SS * DQK;
  const __bf16* vBase = Vt + (int64_t)b * KVR * SS;

  auto stage = [&](int t0) {
    const __bf16* kb = kBase + (int64_t)t0 * DQK;
#pragma unroll
    for (int it = 0; it < 4; it++) gl16(kb + kSrc[it], &lK[(it * 512 + tid) * 8]);
    if (wid < 4) gl16(kb + kSrc[4], &lK[(2048 + tid) * 8]);
    const __bf16* vb = vBase + t0;
#pragma unroll
    for (int it = 0; it < 4; it++) gl16(vb + vSrc[it], &lV[(it * 512 + tid) * 8]);
  };

  const int nsteps = bx * 4 + 4;
  stage(0);
  const int vkey = (p >> 1) & 3;
  for (int st = 0; st < nsteps; st++) {
    const int t0 = st * 32;
    asm volatile("s_waitcnt vmcnt(0)" ::: "memory");
    __builtin_amdgcn_s_barrier();   // tile resident in lK/lV

    // ---- QK^T ----
    f32x4 sc[2]; sc[0] = fz; sc[1] = fz;
#pragma unroll
    for (int kc = 0; kc < 18; kc++) {
#pragma unroll
      for (int n = 0; n < 2; n++) {
        int trow = n * 16 + p;
        bf16x8 bf = *(const bf16x8*)&lK[trow * 576 + (((4 * kc + g) ^ (trow & 7))) * 8];
        sc[n] = mfma16(qreg[kc], bf, sc[n]);
      }
    }
    if (t0 + 31 > qw) {
#pragma unroll
      for (int n = 0; n < 2; n++) {
        int t = t0 + n * 16 + p;
#pragma unroll
        for (int r = 0; r < 4; r++) {
          int q = qw + g * 4 + r;
          if (t > q) sc[n][r] = -1e9f;
        }
      }
    }

    // ---- online softmax with defer-max (T13, THR=8) ----
    float pvv[2][4], es[4];
    int needAny = 0;
#pragma unroll
    for (int r = 0; r < 4; r++) {
      float mx = fmaxf(sc[0][r], sc[1][r]);
#pragma unroll
      for (int mk = 1; mk < 16; mk <<= 1) mx = fmaxf(mx, __shfl_xor(mx, mk, 64));
      if (mx > mrun[r] + 8.f) { es[r] = __expf(mrun[r] - mx); mrun[r] = mx; needAny = 1; }
      else es[r] = 1.f;
      float s0 = __expf(sc[0][r] - mrun[r]);
      float s1 = __expf(sc[1][r] - mrun[r]);
      pvv[0][r] = s0; pvv[1][r] = s1;
      float rs = s0 + s1;
#pragma unroll
      for (int mk = 1; mk < 16; mk <<= 1) rs += __shfl_xor(rs, mk, 64);
      lrun[r] = lrun[r] * es[r] + rs;
    }
    if (__any(needAny)) {
#pragma unroll
      for (int ct = 0; ct < 32; ct++)
#pragma unroll
        for (int r = 0; r < 4; r++) acc[ct][r] *= es[r];
    }

    // ---- P -> LDS (XOR key (row>>1)&3 on 16B granules) ----
#pragma unroll
    for (int n = 0; n < 2; n++)
#pragma unroll
      for (int r = 0; r < 4; r++) {
        int prow = g * 4 + r;
        lP[wid * 512 + prow * 32 + ((n * 16 + p) ^ (((prow >> 1) & 3) * 8))] = (__bf16)pvv[n][r];
      }
    bf16x8 pa = *(const bf16x8*)&lP[wid * 512 + p * 32 + ((g ^ ((p >> 1) & 3)) * 8)];

    // ---- PV ----
#pragma unroll
    for (int ct = 0; ct < 32; ct++) {
      int c = ct * 16 + p;
      bf16x8 bv = *(const bf16x8*)&lV[c * 32 + ((g ^ vkey) * 8)];
      acc[ct] = mfma16(pa, bv, acc[ct]);
    }
    asm volatile("s_waitcnt lgkmcnt(0)" ::: "memory");
    __builtin_amdgcn_s_barrier();   // everyone done reading lK/lV
    if (st + 1 < nsteps) stage(t0 + 32);
  }

#pragma unroll
  for (int r = 0; r < 4; r++) {
    float inv = 1.f / lrun[r];
    int64_t rb = ((int64_t)z * SS + qw + g * 4 + r) * DQK;  // in-place over Qcat
#pragma unroll
    for (int ct = 0; ct < 32; ct++) Olat[rb + ct * 16 + p] = (__bf16)(acc[ct][r] * inv);
  }
}

extern "C" void kernel_launch(void* const* d_in, const int* in_sizes, int n_in,
                              void* d_out, int out_size, void* d_ws, size_t ws_size,
                              hipStream_t stream) {
  const float* x     = (const float*)d_in[0];
  const float* wq    = (const float*)d_in[1];
  const float* wkv_a = (const float*)d_in[2];
  const float* kvw   = (const float*)d_in[3];
  const float* wkv_b = (const float*)d_in[4];
  const float* wo    = (const float*)d_in[5];
  const float* fc    = (const float*)d_in[6];
  const float* fs    = (const float*)d_in[7];
  float* out = (float*)d_out;

  char* base = (char*)d_ws;
  const size_t OFF_KCAT  = 0;
  const size_t OFF_VT    = OFF_KCAT + 9437184ull;
  const size_t OFF_WKVB  = OFF_VT + 8388608ull;
  const size_t OFF_WOT   = OFF_WKVB + 4194304ull;
  const size_t OFF_QCAT  = OFF_WOT + 8388608ull;
  const size_t OFF_OHEAD = OFF_QCAT + 150994944ull;
  const size_t OFF_QFULL = OFF_OHEAD + 33554432ull;
  const size_t TOTAL     = OFF_QFULL + 50331648ull;

  __bf16* Kcat    = (__bf16*)(base + OFF_KCAT);
  __bf16* Vt      = (__bf16*)(base + OFF_VT);
  __bf16* wkvb_bf = (__bf16*)(base + OFF_WKVB);
  __bf16* woT     = (__bf16*)(base + OFF_WOT);
  __bf16* Qcat    = (__bf16*)(base + OFF_QCAT);
  __bf16* o_head  = (__bf16*)(base + OFF_OHEAD);
  __bf16* qfull   = (__bf16*)(base + OFF_QFULL);
  __bf16* wqT    = (__bf16*)(base + OFF_KCAT);
  __bf16* wkvaT  = (__bf16*)(base + OFF_KCAT + 12582912);
  __bf16* xb     = (__bf16*)(base + OFF_QCAT);
  __bf16* kvfull = (__bf16*)(base + OFF_QCAT + 33554432);
  __bf16* wbTn   = (__bf16*)(base + OFF_OHEAD);

  if (ws_size < TOTAL) {
    fprintf(stderr, "kernel_launch: ws too small: need %zu have %zu\n", TOTAL, ws_size);
    return;
  }

  k_cvt<<<8192, 256, 0, stream>>>(x, xb, BB * SS * DIMM);
  k_cvt<<<1024, 256, 0, stream>>>(wkv_b, wkvb_bf, 4096 * 512);
  k_tr<<<dim3(96, 64, 1), dim3(32, 8), 0, stream>>>(wq, wqT, 2048, 3072, 0, 0);
  k_tr<<<dim3(18, 64, 1), dim3(32, 8), 0, stream>>>(wkv_a, wkvaT, 2048, 576, 0, 0);
  k_tr<<<dim3(64, 64, 1), dim3(32, 8), 0, stream>>>(wo, woT, 2048, 2048, 0, 0);
  k_tr<<<dim3(16, 4, 16), dim3(32, 8), 0, stream>>>(wkv_b, wbTn, 128, 512,
                                                    (int64_t)256 * 512, (int64_t)512 * 128);
  k_gemm<false><<<dim3(24, 64, 1), 256, 0, stream>>>(
      xb, wqT, qfull, 3072, 2048, 2048, 2048, 3072, 0, 0, 0, 0, 0, 1, 1.0f);
  k_gemm<false><<<dim3(5, 64, 1), 256, 0, stream>>>(
      xb, wkvaT, kvfull, 576, 2048, 2048, 2048, 576, 0, 0, 0, 0, 0, 1, 1.0f);
  k_kvprep<<<8192, 64, 0, stream>>>(kvfull, kvw, fc, fs, Kcat, Vt);
  k_gemm<false><<<dim3(4, 16, 64), 256, 0, stream>>>(
      qfull, wbTn, Qcat, 512, 128, 3072, 128, 576,
      (int64_t)SS * 3072, (int64_t)QKD, (int64_t)512 * 128,
      (int64_t)HH * SS * DQK, (int64_t)SS * DQK, 16, SCALE_F);
  k_qpe<<<16384, 256, 0, stream>>>(qfull, fc, fs, Qcat);
  // attention: grid (z=64 fastest, y=16 balanced-permuted causal depth)
  k_attn<<<dim3(64, 16), 512, 0, stream>>>(Qcat, Kcat, Vt, Qcat);
  k_gemm<false><<<dim3(1, 16, 64), 256, 0, stream>>>(
      Qcat, wkvb_bf + 128 * 512, o_head, 128, 512, DQK, 512, 2048,
      (int64_t)HH * SS * DQK, (int64_t)SS * DQK, (int64_t)256 * 512,
      (int64_t)SS * 2048, (int64_t)128, 16, 1.0f);
  k_gemm<true><<<dim3(16, 64, 1), 256, 0, stream>>>(
      o_head, woT, out, 2048, 2048, 2048, 2048, 2048, 0, 0, 0, 0, 0, 1, 1.0f);
}

// Round 6
// 1263.588 us; speedup vs baseline: 3.3852x; 3.3852x over previous
//
#include <hip/hip_runtime.h>
#include <hip/hip_bf16.h>
#include <cstdio>
#include <cstdint>

#define BB   4
#define SS   2048
#define DIMM 2048
#define HH   16
#define NOPED 128
#define QKD  192
#define KVR  512
#define DQK  576
#define SCALE_F 0.07216878364870323f  // 192^-0.5

typedef __attribute__((ext_vector_type(4))) float f32x4;
typedef __attribute__((ext_vector_type(8))) __bf16 bf16x8;
typedef __attribute__((ext_vector_type(8))) unsigned short u16x8;

__device__ __forceinline__ f32x4 mfma16(bf16x8 a, bf16x8 b, f32x4 c) {
  return __builtin_amdgcn_mfma_f32_16x16x32_bf16(a, b, c, 0, 0, 0);
}

// async global->LDS, 16B per lane; LDS dest must be wave-uniform base + lane*16
__device__ __forceinline__ void gl16(const __bf16* g, __bf16* l) {
  __builtin_amdgcn_global_load_lds(
      (const __attribute__((address_space(1))) unsigned int*)g,
      (__attribute__((address_space(3))) unsigned int*)l, 16, 0, 0);
}

// ---------------- f32 -> bf16 convert ----------------
__global__ void k_cvt(const float* __restrict__ in, __bf16* __restrict__ out, int n) {
  int i = (blockIdx.x * 256 + threadIdx.x) * 8;
  if (i >= n) return;
  float4 a = *(const float4*)(in + i);
  float4 b = *(const float4*)(in + i + 4);
  bf16x8 v;
  v[0] = (__bf16)a.x; v[1] = (__bf16)a.y; v[2] = (__bf16)a.z; v[3] = (__bf16)a.w;
  v[4] = (__bf16)b.x; v[5] = (__bf16)b.y; v[6] = (__bf16)b.z; v[7] = (__bf16)b.w;
  *(bf16x8*)(out + i) = v;
}

// ---------------- f32 transpose -> bf16 (batched) ----------------
__global__ void k_tr(const float* __restrict__ in, __bf16* __restrict__ out,
                     int R, int C, int64_t inBS, int64_t outBS) {
  in  += (int64_t)blockIdx.z * inBS;
  out += (int64_t)blockIdx.z * outBS;
  __shared__ float t[32][33];
  int c0 = blockIdx.x * 32, r0 = blockIdx.y * 32;
#pragma unroll
  for (int i = 0; i < 4; i++) {
    int r = r0 + threadIdx.y + i * 8, c = c0 + threadIdx.x;
    if (r < R && c < C) t[threadIdx.y + i * 8][threadIdx.x] = in[(int64_t)r * C + c];
  }
  __syncthreads();
#pragma unroll
  for (int i = 0; i < 4; i++) {
    int c = c0 + threadIdx.y + i * 8, r = r0 + threadIdx.x;
    if (c < C && r < R) out[(int64_t)c * R + r] = (__bf16)t[threadIdx.x][threadIdx.y + i * 8];
  }
}

// ---------------- generic batched MFMA GEMM: C = scale * A(M,K) x Bt(N,K)^T ----------------
template <bool OUTF32>
__global__ __launch_bounds__(256) void k_gemm(
    const __bf16* __restrict__ A, const __bf16* __restrict__ Bt, void* __restrict__ Cv,
    int N, int K, int lda, int ldb, int ldc,
    int64_t aSB, int64_t aSH, int64_t bSH, int64_t cSB, int64_t cSH, int Hdiv, float scale) {
  const int z = blockIdx.z;
  const int zb = z / Hdiv, zh = z % Hdiv;
  const int64_t aBase = zb * aSB + zh * aSH;
  const int64_t bBase = zh * bSH;
  const int64_t cBase = zb * cSB + zh * cSH;
  const int n0 = blockIdx.x * 128, m0 = blockIdx.y * 128;
  const int tid = threadIdx.x, lane = tid & 63, wid = tid >> 6;
  const int p = lane & 15, g = lane >> 4;
  const int wr = (wid >> 1) * 64, wc = (wid & 1) * 64;
  __shared__ alignas(16) __bf16 lA[128 * 40];
  __shared__ alignas(16) __bf16 lB[128 * 40];
  const f32x4 fz = {};
  f32x4 acc[4][4];
#pragma unroll
  for (int i = 0; i < 4; i++)
#pragma unroll
    for (int j = 0; j < 4; j++) acc[i][j] = fz;
  const int srow = tid >> 1, shf = tid & 1;
  const __bf16* gA = A + aBase + (int64_t)(m0 + srow) * lda + shf * 16;
  const __bf16* gB = Bt + bBase + (int64_t)(n0 + srow) * ldb + shf * 16;
  const bool bok = (n0 + srow) < N;
  for (int kt = 0; kt < K; kt += 32) {
    u16x8 a0 = *(const u16x8*)(gA + kt);
    u16x8 a1 = *(const u16x8*)(gA + kt + 8);
    u16x8 b0 = {}, b1 = {};
    if (bok) { b0 = *(const u16x8*)(gB + kt); b1 = *(const u16x8*)(gB + kt + 8); }
    __syncthreads();
    *(u16x8*)&lA[srow * 40 + shf * 16]     = a0;
    *(u16x8*)&lA[srow * 40 + shf * 16 + 8] = a1;
    *(u16x8*)&lB[srow * 40 + shf * 16]     = b0;
    *(u16x8*)&lB[srow * 40 + shf * 16 + 8] = b1;
    __syncthreads();
    bf16x8 af[4], bfr[4];
#pragma unroll
    for (int mi = 0; mi < 4; mi++) af[mi]  = *(const bf16x8*)&lA[(wr + mi * 16 + p) * 40 + g * 8];
#pragma unroll
    for (int ni = 0; ni < 4; ni++) bfr[ni] = *(const bf16x8*)&lB[(wc + ni * 16 + p) * 40 + g * 8];
#pragma unroll
    for (int mi = 0; mi < 4; mi++)
#pragma unroll
      for (int ni = 0; ni < 4; ni++) acc[mi][ni] = mfma16(af[mi], bfr[ni], acc[mi][ni]);
  }
#pragma unroll
  for (int mi = 0; mi < 4; mi++) {
#pragma unroll
    for (int ni = 0; ni < 4; ni++) {
      const int n = n0 + wc + ni * 16 + p;
      if (n < N) {
#pragma unroll
        for (int r = 0; r < 4; r++) {
          const int m = m0 + wr + mi * 16 + g * 4 + r;
          float v = acc[mi][ni][r] * scale;
          if (OUTF32) ((float*)Cv)[cBase + (int64_t)m * ldc + n] = v;
          else        ((__bf16*)Cv)[cBase + (int64_t)m * ldc + n] = (__bf16)v;
        }
      }
    }
  }
}

// ---------------- kv prep ----------------
__global__ __launch_bounds__(64) void k_kvprep(
    const __bf16* __restrict__ kvfull, const float* __restrict__ wnorm,
    const float* __restrict__ fc, const float* __restrict__ fs,
    __bf16* __restrict__ Kcat, __bf16* __restrict__ Vt) {
  const int row = blockIdx.x;
  const int lane = threadIdx.x;
  const int b = row >> 11, s = row & 2047;
  const __bf16* src = kvfull + (int64_t)row * DQK;
  bf16x8 v = *(const bf16x8*)(src + lane * 8);
  float f[8], ss = 0.f;
#pragma unroll
  for (int j = 0; j < 8; j++) { f[j] = (float)v[j]; ss += f[j] * f[j]; }
#pragma unroll
  for (int mk = 1; mk < 64; mk <<= 1) ss += __shfl_xor(ss, mk, 64);
  float rn = rsqrtf(ss * (1.f / 512.f) + 1e-6f);
  bf16x8 o;
#pragma unroll
  for (int j = 0; j < 8; j++) o[j] = (__bf16)(f[j] * rn * wnorm[lane * 8 + j]);
  *(bf16x8*)(Kcat + (int64_t)row * DQK + lane * 8) = o;
#pragma unroll
  for (int j = 0; j < 8; j++) Vt[((int64_t)b * KVR + lane * 8 + j) * SS + s] = o[j];
  if (lane < 32) {
    float xr = (float)src[512 + 2 * lane];
    float xi = (float)src[512 + 2 * lane + 1];
    float c = fc[s * 32 + lane], sn = fs[s * 32 + lane];
    Kcat[(int64_t)row * DQK + 512 + 2 * lane]     = (__bf16)(xr * c - xi * sn);
    Kcat[(int64_t)row * DQK + 512 + 2 * lane + 1] = (__bf16)(xr * sn + xi * c);
  }
}

// ---------------- q rope ----------------
__global__ void k_qpe(const __bf16* __restrict__ qfull, const float* __restrict__ fc,
                      const float* __restrict__ fs, __bf16* __restrict__ Qcat) {
  int idx = blockIdx.x * 256 + threadIdx.x;
  if (idx >= BB * HH * SS * 32) return;
  int i = idx & 31, s = (idx >> 5) & 2047, h = (idx >> 16) & 15, b = idx >> 20;
  const __bf16* src = qfull + ((int64_t)(b * SS + s)) * 3072 + h * QKD + NOPED;
  float xr = (float)src[2 * i], xi = (float)src[2 * i + 1];
  float c = fc[s * 32 + i], sn = fs[s * 32 + i];
  __bf16* dst = Qcat + (((int64_t)(b * HH + h)) * SS + s) * DQK + 512;
  dst[2 * i]     = (__bf16)((xr * c - xi * sn) * SCALE_F);
  dst[2 * i + 1] = (__bf16)((xr * sn + xi * c) * SCALE_F);
}

// ---------------- flash attention v6 ----------------
// 256 threads (4 waves x 16 q-rows = 64 q/block) -- round-2's proven no-spill
// register regime (~248 VGPR incl acc). Single-buffered K+V (73728 B LDS) ->
// 2 blocks/CU co-resident; the sibling block hides vmcnt(0)+barrier stalls.
// Zero-conflict swizzles from v5 kept (measured SQ_LDS_BANK_CONFLICT == 0).
// Grid (8=xcd, 256=w): id%8 == blockIdx.x pins each z-octet to one XCD
// (per-XCD K/V ~= 4.4 MB ~= its L2); w decodes to (z, depth) with per-CU
// work exactly balanced (pairing perm: every class sums to 124).
__global__ __launch_bounds__(256) void k_attn(
    const __bf16* __restrict__ Qcat, const __bf16* __restrict__ Kcat,
    const __bf16* __restrict__ Vt, __bf16* __restrict__ Olat) {
  const int gx = blockIdx.x;            // XCD selector
  const int w  = blockIdx.y;
  const int z  = gx * 8 + (w & 7);      // (b,h): b = z>>4
  const int yv = w >> 3;                // depth slot 0..31
  const int kk = yv >> 2, cc = yv & 3;
  const int bx = (kk & 1) ? (31 - ((kk - 1) << 1) - cc) : ((kk << 1) + cc);
  const int b = z >> 4;
  const int q0 = bx * 64;
  const int tid = threadIdx.x, lane = tid & 63, wid = tid >> 6;
  const int p = lane & 15, g = lane >> 4;
  const int qw = q0 + wid * 16;
  __shared__ alignas(16) __bf16 lK[32 * 576];   // 36864 B
  __shared__ alignas(16) __bf16 lV[512 * 32];   // 32768 B
  __shared__ alignas(16) __bf16 lP[4 * 512];    //  4096 B  (total 73728)

  // ---- step-invariant staging offsets (linear dest, source-side swizzle) ----
  int kSrc[9], vSrc[8];
#pragma unroll
  for (int it = 0; it < 9; it++) {
    int slot = it * 256 + tid;
    int row = slot / 72, u = slot - row * 72;
    kSrc[it] = row * DQK + ((u ^ (row & 7)) * 8);
  }
#pragma unroll
  for (int it = 0; it < 8; it++) {
    int slot = it * 256 + tid;
    int c = slot >> 2, u = slot & 3;
    vSrc[it] = c * SS + ((u ^ ((c >> 1) & 3)) * 8);
  }

  // ---- Q hoist ----
  bf16x8 qreg[18];
  {
    const __bf16* qb = Qcat + ((int64_t)z * SS + qw + p) * DQK + g * 8;
#pragma unroll
    for (int kc = 0; kc < 18; kc++) qreg[kc] = *(const bf16x8*)(qb + kc * 32);
  }
  const f32x4 fz = {};
  f32x4 acc[32];
#pragma unroll
  for (int ct = 0; ct < 32; ct++) acc[ct] = fz;
  float mrun[4] = {-1e30f, -1e30f, -1e30f, -1e30f};
  float lrun[4] = {0.f, 0.f, 0.f, 0.f};

  const __bf16* kBase = Kcat + (int64_t)b * SS * DQK;
  const __bf16* vBase = Vt + (int64_t)b * KVR * SS;

  auto stage = [&](int t0) {
    const __bf16* kb = kBase + (int64_t)t0 * DQK;
#pragma unroll
    for (int it = 0; it < 9; it++) gl16(kb + kSrc[it], &lK[(it * 256 + tid) * 8]);
    const __bf16* vb = vBase + t0;
#pragma unroll
    for (int it = 0; it < 8; it++) gl16(vb + vSrc[it], &lV[(it * 256 + tid) * 8]);
  };

  const int nsteps = bx * 2 + 2;
  stage(0);
  const int vkey = (p >> 1) & 3;
  for (int st = 0; st < nsteps; st++) {
    const int t0 = st * 32;
    asm volatile("s_waitcnt vmcnt(0)" ::: "memory");
    __builtin_amdgcn_s_barrier();   // tile resident in lK/lV

    // ---- QK^T ----
    f32x4 sc[2]; sc[0] = fz; sc[1] = fz;
#pragma unroll
    for (int kc = 0; kc < 18; kc++) {
#pragma unroll
      for (int n = 0; n < 2; n++) {
        int trow = n * 16 + p;
        bf16x8 bf = *(const bf16x8*)&lK[trow * 576 + (((4 * kc + g) ^ (trow & 7))) * 8];
        sc[n] = mfma16(qreg[kc], bf, sc[n]);
      }
    }
    if (t0 + 31 > qw) {
#pragma unroll
      for (int n = 0; n < 2; n++) {
        int t = t0 + n * 16 + p;
#pragma unroll
        for (int r = 0; r < 4; r++) {
          int q = qw + g * 4 + r;
          if (t > q) sc[n][r] = -1e9f;
        }
      }
    }

    // ---- online softmax with defer-max (T13, THR=8) ----
    float pvv[2][4], es[4];
    int needAny = 0;
#pragma unroll
    for (int r = 0; r < 4; r++) {
      float mx = fmaxf(sc[0][r], sc[1][r]);
#pragma unroll
      for (int mk = 1; mk < 16; mk <<= 1) mx = fmaxf(mx, __shfl_xor(mx, mk, 64));
      if (mx > mrun[r] + 8.f) { es[r] = __expf(mrun[r] - mx); mrun[r] = mx; needAny = 1; }
      else es[r] = 1.f;
      float s0 = __expf(sc[0][r] - mrun[r]);
      float s1 = __expf(sc[1][r] - mrun[r]);
      pvv[0][r] = s0; pvv[1][r] = s1;
      float rs = s0 + s1;
#pragma unroll
      for (int mk = 1; mk < 16; mk <<= 1) rs += __shfl_xor(rs, mk, 64);
      lrun[r] = lrun[r] * es[r] + rs;
    }
    if (__any(needAny)) {
#pragma unroll
      for (int ct = 0; ct < 32; ct++)
#pragma unroll
        for (int r = 0; r < 4; r++) acc[ct][r] *= es[r];
    }

    // ---- P -> LDS (XOR key (row>>1)&3 on 16B granules) ----
#pragma unroll
    for (int n = 0; n < 2; n++)
#pragma unroll
      for (int r = 0; r < 4; r++) {
        int prow = g * 4 + r;
        lP[wid * 512 + prow * 32 + ((n * 16 + p) ^ (((prow >> 1) & 3) * 8))] = (__bf16)pvv[n][r];
      }
    bf16x8 pa = *(const bf16x8*)&lP[wid * 512 + p * 32 + ((g ^ ((p >> 1) & 3)) * 8)];

    // ---- PV ----
#pragma unroll
    for (int ct = 0; ct < 32; ct++) {
      int c = ct * 16 + p;
      bf16x8 bv = *(const bf16x8*)&lV[c * 32 + ((g ^ vkey) * 8)];
      acc[ct] = mfma16(pa, bv, acc[ct]);
    }
    asm volatile("s_waitcnt lgkmcnt(0)" ::: "memory");
    __builtin_amdgcn_s_barrier();   // everyone done reading lK/lV
    if (st + 1 < nsteps) stage(t0 + 32);
  }

#pragma unroll
  for (int r = 0; r < 4; r++) {
    float inv = 1.f / lrun[r];
    int64_t rb = ((int64_t)z * SS + qw + g * 4 + r) * DQK;  // in-place over Qcat
#pragma unroll
    for (int ct = 0; ct < 32; ct++) Olat[rb + ct * 16 + p] = (__bf16)(acc[ct][r] * inv);
  }
}

extern "C" void kernel_launch(void* const* d_in, const int* in_sizes, int n_in,
                              void* d_out, int out_size, void* d_ws, size_t ws_size,
                              hipStream_t stream) {
  const float* x     = (const float*)d_in[0];
  const float* wq    = (const float*)d_in[1];
  const float* wkv_a = (const float*)d_in[2];
  const float* kvw   = (const float*)d_in[3];
  const float* wkv_b = (const float*)d_in[4];
  const float* wo    = (const float*)d_in[5];
  const float* fc    = (const float*)d_in[6];
  const float* fs    = (const float*)d_in[7];
  float* out = (float*)d_out;

  char* base = (char*)d_ws;
  const size_t OFF_KCAT  = 0;
  const size_t OFF_VT    = OFF_KCAT + 9437184ull;
  const size_t OFF_WKVB  = OFF_VT + 8388608ull;
  const size_t OFF_WOT   = OFF_WKVB + 4194304ull;
  const size_t OFF_QCAT  = OFF_WOT + 8388608ull;
  const size_t OFF_OHEAD = OFF_QCAT + 150994944ull;
  const size_t OFF_QFULL = OFF_OHEAD + 33554432ull;
  const size_t TOTAL     = OFF_QFULL + 50331648ull;

  __bf16* Kcat    = (__bf16*)(base + OFF_KCAT);
  __bf16* Vt      = (__bf16*)(base + OFF_VT);
  __bf16* wkvb_bf = (__bf16*)(base + OFF_WKVB);
  __bf16* woT     = (__bf16*)(base + OFF_WOT);
  __bf16* Qcat    = (__bf16*)(base + OFF_QCAT);
  __bf16* o_head  = (__bf16*)(base + OFF_OHEAD);
  __bf16* qfull   = (__bf16*)(base + OFF_QFULL);
  __bf16* wqT    = (__bf16*)(base + OFF_KCAT);
  __bf16* wkvaT  = (__bf16*)(base + OFF_KCAT + 12582912);
  __bf16* xb     = (__bf16*)(base + OFF_QCAT);
  __bf16* kvfull = (__bf16*)(base + OFF_QCAT + 33554432);
  __bf16* wbTn   = (__bf16*)(base + OFF_OHEAD);

  if (ws_size < TOTAL) {
    fprintf(stderr, "kernel_launch: ws too small: need %zu have %zu\n", TOTAL, ws_size);
    return;
  }

  k_cvt<<<8192, 256, 0, stream>>>(x, xb, BB * SS * DIMM);
  k_cvt<<<1024, 256, 0, stream>>>(wkv_b, wkvb_bf, 4096 * 512);
  k_tr<<<dim3(96, 64, 1), dim3(32, 8), 0, stream>>>(wq, wqT, 2048, 3072, 0, 0);
  k_tr<<<dim3(18, 64, 1), dim3(32, 8), 0, stream>>>(wkv_a, wkvaT, 2048, 576, 0, 0);
  k_tr<<<dim3(64, 64, 1), dim3(32, 8), 0, stream>>>(wo, woT, 2048, 2048, 0, 0);
  k_tr<<<dim3(16, 4, 16), dim3(32, 8), 0, stream>>>(wkv_b, wbTn, 128, 512,
                                                    (int64_t)256 * 512, (int64_t)512 * 128);
  k_gemm<false><<<dim3(24, 64, 1), 256, 0, stream>>>(
      xb, wqT, qfull, 3072, 2048, 2048, 2048, 3072, 0, 0, 0, 0, 0, 1, 1.0f);
  k_gemm<false><<<dim3(5, 64, 1), 256, 0, stream>>>(
      xb, wkvaT, kvfull, 576, 2048, 2048, 2048, 576, 0, 0, 0, 0, 0, 1, 1.0f);
  k_kvprep<<<8192, 64, 0, stream>>>(kvfull, kvw, fc, fs, Kcat, Vt);
  k_gemm<false><<<dim3(4, 16, 64), 256, 0, stream>>>(
      qfull, wbTn, Qcat, 512, 128, 3072, 128, 576,
      (int64_t)SS * 3072, (int64_t)QKD, (int64_t)512 * 128,
      (int64_t)HH * SS * DQK, (int64_t)SS * DQK, 16, SCALE_F);
  k_qpe<<<16384, 256, 0, stream>>>(qfull, fc, fs, Qcat);
  // attention: grid (8=xcd, 256=w)
  k_attn<<<dim3(8, 256), 256, 0, stream>>>(Qcat, Kcat, Vt, Qcat);
  k_gemm<false><<<dim3(1, 16, 64), 256, 0, stream>>>(
      Qcat, wkvb_bf + 128 * 512, o_head, 128, 512, DQK, 512, 2048,
      (int64_t)HH * SS * DQK, (int64_t)SS * DQK, (int64_t)256 * 512,
      (int64_t)SS * 2048, (int64_t)128, 16, 1.0f);
  k_gemm<true><<<dim3(16, 64, 1), 256, 0, stream>>>(
      o_head, woT, out, 2048, 2048, 2048, 2048, 2048, 0, 0, 0, 0, 0, 1, 1.0f);
}